// Round 1
// baseline (16980.251 us; speedup 1.0000x reference)
//
#include <hip/hip_runtime.h>
#include <hip/hip_bf16.h>
#include <math.h>

// ---------------------------------------------------------------------------
// Problem constants (ResonanceTransformer): B=16,S=512,D=512,F=2048,L=6,V=10000
// M = B*S = 8192 tokens.
// ---------------------------------------------------------------------------
#define MTOK   8192
#define DMODEL 512
#define DFF    2048
#define NLAYER 6
#define VOCAB  10000
#define NHEAD  8
#define DHEAD  64

// ---------------------------------------------------------------------------
// ws layout (bytes)
// ---------------------------------------------------------------------------
// X    : 8192*512 f32                      @ 0
// Y    : 8192*512 f32                      @ 16 MB
// BUF  : 8192*2048 f32 (qkv / z / ff1)     @ 32 MB
// WP   : 1048576 f32 (pruned weight reuse) @ 96 MB
// HIST : 36*4096 u32                       @ 100 MB
// STATE: 36 * 32 B                         @ +hist
// THR  : 18 * f64                          @ +state
static const size_t X_B     = 0;
static const size_t Y_B     = (size_t)MTOK * DMODEL * 4;                  // 16,777,216
static const size_t BUF_B   = Y_B * 2;                                     // 33,554,432
static const size_t WP_B    = BUF_B + (size_t)MTOK * DFF * 4;              // 100,663,296
static const size_t HIST_B  = WP_B + (size_t)1048576 * 4;                  // 104,857,600
static const size_t STATE_B = HIST_B + (size_t)36 * 4096 * 4;              // 105,447,424
static const size_t THR_B   = STATE_B + (size_t)36 * 32;                   // 105,448,576
static const size_t WS_NEED = THR_B + 18 * 8;

struct PState {
    double lo, hi;
    unsigned int rank;
    unsigned int pad;
    unsigned long long found;   // f64 bits of captured order statistic
};

// ---------------------------------------------------------------------------
// prune: |etched| chain.  f32 sin (matches numpy f32 sin of f32 product),
// then f64 for theta/cos/bloom/etched (numpy promotes via f64 linspace).
// ---------------------------------------------------------------------------
__device__ __forceinline__ double etched_abs(float wv, int i, double step, double invn)
{
    float b0 = sinf(wv * 3.14159274f);            // f32 pi, f32 product
    b0 = fminf(1.0f, fmaxf(-1.0f, b0));
    double theta = step * (double)i;              // linspace(0, s, s)[i] = i*s/(s-1)
    double c = cos(theta * invn + 2.0943951023931953);   // theta/s + 2*pi/3
    double bl = (double)b0;
    double bloom = bl + bl * c * 1.5;
    double e = cos(bloom * 9.869604401089358)     // pi^2
             + bloom * bloom * 0.003183098861837907;     // 0.01/pi
    return fabs(e);
}

// matrix table: m = 3*l + {0: in_proj(1536x512), 1: lin1(2048x512), 2: lin2(512x2048)}
__device__ __forceinline__ void prune_matrix(int m, const float* ipw, const float* w1,
                                             const float* w2, const float** w, int* n)
{
    int l = m / 3, j = m % 3;
    if (j == 0)      { *w = ipw + (size_t)l * 786432;  *n = 786432;  }
    else if (j == 1) { *w = w1  + (size_t)l * 1048576; *n = 1048576; }
    else             { *w = w2  + (size_t)l * 1048576; *n = 1048576; }
}

__global__ __launch_bounds__(256) void k_prune_init(unsigned int* hist, PState* st)
{
    int gid = blockIdx.x * 256 + threadIdx.x;
    for (int i = gid; i < 36 * 4096; i += gridDim.x * 256) hist[i] = 0u;
    if (gid < 36) {
        int m = gid >> 1;
        int n = (m % 3 == 0) ? 786432 : 1048576;
        st[gid].lo = 0.0;
        st[gid].hi = 1.03;                     // > max possible |etched| (~1.02)
        st[gid].rank = (unsigned)(n / 4 - 1 + (gid & 1));   // k0 and k0+1
        st[gid].found = 0x7FF0000000000000ULL; // +inf
    }
}

__global__ __launch_bounds__(256) void k_prune_hist(const float* ipw, const float* w1,
                                                    const float* w2, unsigned int* hist,
                                                    PState* st)
{
    int m = blockIdx.x >> 6;
    int chunk = blockIdx.x & 63;
    const float* w; int n;
    prune_matrix(m, ipw, w1, w2, &w, &n);
    __shared__ unsigned int h[2][4096];
    for (int i = threadIdx.x; i < 8192; i += 256) ((unsigned int*)h)[i] = 0u;
    __syncthreads();
    double lo0 = st[2*m].lo,   hi0 = st[2*m].hi;
    double lo1 = st[2*m+1].lo, hi1 = st[2*m+1].hi;
    double sc0 = 4096.0 / (hi0 - lo0);
    double sc1 = 4096.0 / (hi1 - lo1);
    double step = (double)n / (double)(n - 1);
    double invn = 1.0 / (double)n;
    int per = (n + 63) >> 6;
    int i0 = chunk * per;
    int i1 = min(n, i0 + per);
    for (int i = i0 + (int)threadIdx.x; i < i1; i += 256) {
        double a = etched_abs(w[i], i, step, invn);
        if (a >= lo0 && a < hi0) {
            int bin = (int)((a - lo0) * sc0); if (bin > 4095) bin = 4095;
            atomicAdd(&h[0][bin], 1u);
        }
        if (a >= lo1 && a < hi1) {
            int bin = (int)((a - lo1) * sc1); if (bin > 4095) bin = 4095;
            atomicAdd(&h[1][bin], 1u);
        }
    }
    __syncthreads();
    for (int i = threadIdx.x; i < 4096; i += 256) {
        if (h[0][i]) atomicAdd(&hist[(size_t)(2*m) * 4096 + i], h[0][i]);
        if (h[1][i]) atomicAdd(&hist[(size_t)(2*m+1) * 4096 + i], h[1][i]);
    }
}

__global__ __launch_bounds__(256) void k_prune_select(unsigned int* hist, PState* st)
{
    int s = blockIdx.x;
    __shared__ unsigned int h[4096];
    unsigned int* gh = hist + (size_t)s * 4096;
    for (int i = threadIdx.x; i < 4096; i += 256) { h[i] = gh[i]; gh[i] = 0u; }
    __syncthreads();
    if (threadIdx.x == 0) {
        PState ps = st[s];
        unsigned int r = ps.rank;
        unsigned int acc = 0;
        int bsel = -1; unsigned int newr = 0;
        for (int bi = 0; bi < 4096; ++bi) {
            unsigned int c = h[bi];
            if (bsel < 0 && r < acc + c) { bsel = bi; newr = r - acc; }
            acc += c;
        }
        if (bsel < 0) {   // fp-edge migration fallback
            for (int bi = 4095; bi >= 0; --bi)
                if (h[bi]) { bsel = bi; newr = h[bi] - 1; break; }
            if (bsel < 0) { bsel = 0; newr = 0; }
        }
        double width = (ps.hi - ps.lo) / 4096.0;
        st[s].lo = ps.lo + width * bsel;
        st[s].hi = ps.lo + width * (bsel + 1);
        st[s].rank = newr;
    }
}

__global__ __launch_bounds__(256) void k_prune_capture(const float* ipw, const float* w1,
                                                       const float* w2, PState* st)
{
    int m = blockIdx.x >> 6;
    int chunk = blockIdx.x & 63;
    const float* w; int n;
    prune_matrix(m, ipw, w1, w2, &w, &n);
    double lo0 = st[2*m].lo, lo1 = st[2*m+1].lo;
    double step = (double)n / (double)(n - 1);
    double invn = 1.0 / (double)n;
    unsigned long long mn0 = 0x7FF0000000000000ULL, mn1 = 0x7FF0000000000000ULL;
    int per = (n + 63) >> 6;
    int i0 = chunk * per;
    int i1 = min(n, i0 + per);
    for (int i = i0 + (int)threadIdx.x; i < i1; i += 256) {
        double a = etched_abs(w[i], i, step, invn);
        unsigned long long bits = (unsigned long long)__double_as_longlong(a);
        if (a >= lo0 && bits < mn0) mn0 = bits;
        if (a >= lo1 && bits < mn1) mn1 = bits;
    }
    __shared__ unsigned long long sm[2];
    if (threadIdx.x == 0) { sm[0] = 0x7FF0000000000000ULL; sm[1] = 0x7FF0000000000000ULL; }
    __syncthreads();
    atomicMin(&sm[0], mn0);
    atomicMin(&sm[1], mn1);
    __syncthreads();
    if (threadIdx.x == 0) {
        atomicMin(&st[2*m].found, sm[0]);
        atomicMin(&st[2*m+1].found, sm[1]);
    }
}

__global__ void k_prune_thr(PState* st, double* thr)
{
    int m = threadIdx.x;
    if (m < 18) {
        double v0 = __longlong_as_double((long long)st[2*m].found);
        double v1 = __longlong_as_double((long long)st[2*m+1].found);
        thr[m] = v0 + 0.75 * (v1 - v0);    // np.quantile linear interp, frac=0.75
    }
}

__global__ __launch_bounds__(256) void k_apply_mask(const float* __restrict__ w,
                                                    float* __restrict__ out,
                                                    const double* __restrict__ thr,
                                                    int m, int n)
{
    double T = thr[m];
    double step = (double)n / (double)(n - 1);
    double invn = 1.0 / (double)n;
    for (int i = blockIdx.x * 256 + threadIdx.x; i < n; i += gridDim.x * 256) {
        double a = etched_abs(w[i], i, step, invn);
        out[i] = (a > T) ? w[i] : 0.0f;
    }
}

// ---------------------------------------------------------------------------
// embedding: x[t,d] = emb[src[t],d]*sqrt(512) + pos[t%512, d]
// ---------------------------------------------------------------------------
__global__ __launch_bounds__(256) void k_embed(const int* __restrict__ src,
                                               const float* __restrict__ emb,
                                               const float* __restrict__ pos,
                                               float* __restrict__ x)
{
    int t = blockIdx.x;
    int tid = threadIdx.x;
    int v = src[t];
    int s = t & 511;
    const float* e = emb + (size_t)v * DMODEL;
    const float* p = pos + (size_t)s * DMODEL;
    float* xo = x + (size_t)t * DMODEL;
    xo[tid]       = e[tid]       * 22.627416997969522f + p[tid];
    xo[tid + 256] = e[tid + 256] * 22.627416997969522f + p[tid + 256];
}

// ---------------------------------------------------------------------------
// GEMM: C[M,N] = A[M,K] @ B[N,K]^T + bias[N]  (optional relu)
// 128x128x16 tiles, 256 threads, 8x8 per thread, transposed LDS for float4 reads.
// Requires M%128==0, K%16==0 (true for all calls). N guarded.
// ---------------------------------------------------------------------------
__global__ __launch_bounds__(256) void k_gemm(const float* __restrict__ A,
                                              const float* __restrict__ B,
                                              const float* __restrict__ bias,
                                              float* __restrict__ C,
                                              int M, int N, int K, int relu)
{
    __shared__ float As[16][132];
    __shared__ float Bs[16][132];
    int colBase = blockIdx.x * 128;
    int rowBase = blockIdx.y * 128;
    int t = threadIdx.x;
    int tr = (t >> 4) << 2;   // 0..60
    int tc = (t & 15) << 2;   // 0..60
    float acc[8][8];
#pragma unroll
    for (int r = 0; r < 8; ++r)
#pragma unroll
        for (int c = 0; c < 8; ++c) acc[r][c] = 0.0f;

    for (int k0 = 0; k0 < K; k0 += 16) {
        __syncthreads();
#pragma unroll
        for (int u = 0; u < 2; ++u) {
            int f = t + u * 256;          // 0..511 float4 slots (128 rows x 4)
            int row = f >> 2;
            int c4 = (f & 3) << 2;
            float4 av = *(const float4*)(A + (size_t)(rowBase + row) * K + (k0 + c4));
            As[c4 + 0][row] = av.x; As[c4 + 1][row] = av.y;
            As[c4 + 2][row] = av.z; As[c4 + 3][row] = av.w;
            int nrow = colBase + row;
            float4 bv = make_float4(0.f, 0.f, 0.f, 0.f);
            if (nrow < N) bv = *(const float4*)(B + (size_t)nrow * K + (k0 + c4));
            Bs[c4 + 0][row] = bv.x; Bs[c4 + 1][row] = bv.y;
            Bs[c4 + 2][row] = bv.z; Bs[c4 + 3][row] = bv.w;
        }
        __syncthreads();
#pragma unroll
        for (int kk = 0; kk < 16; ++kk) {
            float4 a0 = *(const float4*)&As[kk][tr];
            float4 a1 = *(const float4*)&As[kk][tr + 64];
            float4 b0 = *(const float4*)&Bs[kk][tc];
            float4 b1 = *(const float4*)&Bs[kk][tc + 64];
            float ar[8] = {a0.x, a0.y, a0.z, a0.w, a1.x, a1.y, a1.z, a1.w};
            float br[8] = {b0.x, b0.y, b0.z, b0.w, b1.x, b1.y, b1.z, b1.w};
#pragma unroll
            for (int r = 0; r < 8; ++r)
#pragma unroll
                for (int c = 0; c < 8; ++c)
                    acc[r][c] = fmaf(ar[r], br[c], acc[r][c]);
        }
    }
#pragma unroll
    for (int r = 0; r < 8; ++r) {
        int row = rowBase + ((r >> 2) << 6) + tr + (r & 3);
#pragma unroll
        for (int c = 0; c < 8; ++c) {
            int col = colBase + ((c >> 2) << 6) + tc + (c & 3);
            if (col < N) {
                float v = acc[r][c] + bias[col];
                if (relu) v = fmaxf(v, 0.0f);
                C[(size_t)row * N + col] = v;
            }
        }
    }
}

// ---------------------------------------------------------------------------
// flash attention: block = 128 threads (2 waves), 32 q-rows per block,
// K/V streamed in 64-row LDS tiles with online softmax.
// qkv layout: [8192][1536] (q|k|v each 512, head h at h*64).
// ---------------------------------------------------------------------------
__global__ __launch_bounds__(128) void k_attn(const float* __restrict__ qkv,
                                              float* __restrict__ out)
{
    __shared__ float Qs[32 * 64];
    __shared__ float Ks[64 * 65];
    __shared__ float Vs[64 * 64];
    __shared__ float Os[32 * 64];
    __shared__ float mS[32], lS[32];
    int bh = blockIdx.x;
    int b = bh >> 3, h = bh & 7;
    int qt = blockIdx.y;                    // 0..15 (32-row q tiles)
    int t = threadIdx.x;
    int w = t >> 6, lane = t & 63;
    size_t rowq = (size_t)(b * 512 + qt * 32);

#pragma unroll
    for (int u = 0; u < 16; ++u) {          // 2048 Q elements
        int idx = t + u * 128;
        int r = idx >> 6, d = idx & 63;
        Qs[r * 64 + d] = qkv[(rowq + r) * 1536 + h * 64 + d];
    }
#pragma unroll
    for (int u = 0; u < 16; ++u) Os[t + u * 128] = 0.0f;
    if (t < 32) { mS[t] = -INFINITY; lS[t] = 0.0f; }

    for (int kt = 0; kt < 8; ++kt) {
        __syncthreads();
        size_t rowk = (size_t)(b * 512 + kt * 64);
#pragma unroll
        for (int u = 0; u < 32; ++u) {      // 4096 K + 4096 V elements
            int idx = t + u * 128;
            int r = idx >> 6, d = idx & 63;
            size_t g = (rowk + r) * 1536 + h * 64 + d;
            Ks[r * 65 + d] = qkv[g + 512];
            Vs[r * 64 + d] = qkv[g + 1024];
        }
        __syncthreads();
        for (int i = 0; i < 16; ++i) {
            int r = w * 16 + i;             // 0..31
            float s = 0.0f;
#pragma unroll
            for (int d = 0; d < 64; ++d)
                s = fmaf(Qs[r * 64 + d], Ks[lane * 65 + d], s);
            s *= 0.125f;                    // 1/sqrt(64)
            float mx = s;
#pragma unroll
            for (int off = 32; off; off >>= 1) mx = fmaxf(mx, __shfl_xor(mx, off, 64));
            float mold = mS[r];
            float mn = fmaxf(mold, mx);
            float alpha = expf(mold - mn);  // first tile: exp(-inf)=0
            float p = expf(s - mn);
            float rs = p;
#pragma unroll
            for (int off = 32; off; off >>= 1) rs += __shfl_xor(rs, off, 64);
            lS[r] = lS[r] * alpha + rs;
            mS[r] = mn;
            float acc = Os[r * 64 + lane] * alpha;
#pragma unroll
            for (int c = 0; c < 64; ++c)
                acc = fmaf(__shfl(p, c, 64), Vs[c * 64 + lane], acc);
            Os[r * 64 + lane] = acc;
        }
    }
#pragma unroll
    for (int i = 0; i < 16; ++i) {
        int r = w * 16 + i;
        out[(rowq + r) * 512 + h * 64 + lane] = Os[r * 64 + lane] / lS[r];
    }
}

// ---------------------------------------------------------------------------
// residual + layernorm: out = LN(x + r)*g + b   (block per token, D=512)
// ---------------------------------------------------------------------------
__global__ __launch_bounds__(256) void k_ln(const float* x, const float* r,
                                            const float* __restrict__ g,
                                            const float* __restrict__ b,
                                            float* out)
{
    int t = blockIdx.x, tid = threadIdx.x;
    size_t base = (size_t)t * DMODEL;
    float a0 = x[base + tid]       + r[base + tid];
    float a1 = x[base + tid + 256] + r[base + tid + 256];
    float s = a0 + a1;
    float q = fmaf(a0, a0, a1 * a1);
#pragma unroll
    for (int off = 32; off; off >>= 1) {
        s += __shfl_xor(s, off, 64);
        q += __shfl_xor(q, off, 64);
    }
    __shared__ float sw[8];
    int w = tid >> 6, lane = tid & 63;
    if (lane == 0) { sw[w] = s; sw[4 + w] = q; }
    __syncthreads();
    s = sw[0] + sw[1] + sw[2] + sw[3];
    q = sw[4] + sw[5] + sw[6] + sw[7];
    float mean = s * (1.0f / 512.0f);
    float var = q * (1.0f / 512.0f) - mean * mean;
    float inv = 1.0f / sqrtf(var + 1e-5f);
    out[base + tid]       = (a0 - mean) * inv * g[tid]       + b[tid];
    out[base + tid + 256] = (a1 - mean) * inv * g[tid + 256] + b[tid + 256];
}

// ---------------------------------------------------------------------------
// host side
// ---------------------------------------------------------------------------
static inline void launch_gemm(const float* A, const float* B, const float* bias,
                               float* C, int M, int N, int K, int relu,
                               hipStream_t stream)
{
    dim3 grid((N + 127) / 128, M / 128);
    k_gemm<<<grid, 256, 0, stream>>>(A, B, bias, C, M, N, K, relu);
}

extern "C" void kernel_launch(void* const* d_in, const int* in_sizes, int n_in,
                              void* d_out, int out_size, void* d_ws, size_t ws_size,
                              hipStream_t stream)
{
    (void)in_sizes; (void)n_in; (void)out_size;
    if (ws_size < WS_NEED) return;   // need ~106 MB of workspace

    const int*   src = (const int*)  d_in[0];
    const float* emb = (const float*)d_in[1];
    const float* pos = (const float*)d_in[2];
    const float* ipw = (const float*)d_in[3];
    const float* ipb = (const float*)d_in[4];
    const float* opw = (const float*)d_in[5];
    const float* opb = (const float*)d_in[6];
    const float* g1  = (const float*)d_in[7];
    const float* b1  = (const float*)d_in[8];
    const float* g2  = (const float*)d_in[9];
    const float* b2  = (const float*)d_in[10];
    const float* w1  = (const float*)d_in[11];
    const float* bb1 = (const float*)d_in[12];
    const float* w2  = (const float*)d_in[13];
    const float* bb2 = (const float*)d_in[14];
    const float* ow  = (const float*)d_in[15];
    const float* ob  = (const float*)d_in[16];

    char* ws = (char*)d_ws;
    float* X   = (float*)(ws + X_B);
    float* Y   = (float*)(ws + Y_B);
    float* BUF = (float*)(ws + BUF_B);
    float* WP  = (float*)(ws + WP_B);
    unsigned int* HIST = (unsigned int*)(ws + HIST_B);
    PState* ST = (PState*)(ws + STATE_B);
    double* THR = (double*)(ws + THR_B);
    float* OUT = (float*)d_out;

    // embedding
    k_embed<<<MTOK, 256, 0, stream>>>(src, emb, pos, X);

    // prune thresholds for all 18 matrices (batched 3-level histogram select)
    k_prune_init<<<64, 256, 0, stream>>>(HIST, ST);
    for (int lev = 0; lev < 3; ++lev) {
        k_prune_hist<<<18 * 64, 256, 0, stream>>>(ipw, w1, w2, HIST, ST);
        k_prune_select<<<36, 256, 0, stream>>>(HIST, ST);
    }
    k_prune_capture<<<18 * 64, 256, 0, stream>>>(ipw, w1, w2, ST);
    k_prune_thr<<<1, 32, 0, stream>>>(ST, THR);

    for (int l = 0; l < NLAYER; ++l) {
        // qkv = x @ prune(in_proj_w)^T + b
        k_apply_mask<<<1024, 256, 0, stream>>>(ipw + (size_t)l * 786432, WP, THR,
                                               3 * l + 0, 786432);
        launch_gemm(X, WP, ipb + (size_t)l * 1536, BUF, MTOK, 1536, DMODEL, 0, stream);
        // attention
        k_attn<<<dim3(128, 16), 128, 0, stream>>>(BUF, Y);
        // out projection (raw weights) -> BUF (z)
        launch_gemm(Y, opw + (size_t)l * 262144, opb + (size_t)l * 512, BUF,
                    MTOK, DMODEL, DMODEL, 0, stream);
        // x = LN(x + z)
        k_ln<<<MTOK, 256, 0, stream>>>(X, BUF, g1 + (size_t)l * 512,
                                       b1 + (size_t)l * 512, X);
        // ff1 = relu(x @ prune(lin1_w)^T + b)
        k_apply_mask<<<1024, 256, 0, stream>>>(w1 + (size_t)l * 1048576, WP, THR,
                                               3 * l + 1, 1048576);
        launch_gemm(X, WP, bb1 + (size_t)l * 2048, BUF, MTOK, DFF, DMODEL, 1, stream);
        // ff2 = ff1 @ prune(lin2_w)^T + b -> Y
        k_apply_mask<<<1024, 256, 0, stream>>>(w2 + (size_t)l * 1048576, WP, THR,
                                               3 * l + 2, 1048576);
        launch_gemm(BUF, WP, bb2 + (size_t)l * 512, Y, MTOK, DMODEL, DFF, 0, stream);
        // x = LN(x + ff)
        k_ln<<<MTOK, 256, 0, stream>>>(X, Y, g2 + (size_t)l * 512,
                                       b2 + (size_t)l * 512, X);
    }

    // logits = x @ out_w^T + out_b
    launch_gemm(X, ow, ob, OUT, MTOK, VOCAB, DMODEL, 0, stream);
}

// Round 2
// 8209.113 us; speedup vs baseline: 2.0685x; 2.0685x over previous
//
#include <hip/hip_runtime.h>
#include <hip/hip_bf16.h>
#include <math.h>

// ---------------------------------------------------------------------------
// Problem constants (ResonanceTransformer): B=16,S=512,D=512,F=2048,L=6,V=10000
// M = B*S = 8192 tokens.
// ---------------------------------------------------------------------------
#define MTOK   8192
#define DMODEL 512
#define DFF    2048
#define NLAYER 6
#define VOCAB  10000
#define NHEAD  8
#define DHEAD  64

// ---------------------------------------------------------------------------
// ws layout (bytes)
// ---------------------------------------------------------------------------
static const size_t X_B     = 0;
static const size_t Y_B     = (size_t)MTOK * DMODEL * 4;                  // 16,777,216
static const size_t BUF_B   = Y_B * 2;                                     // 33,554,432
static const size_t WP_B    = BUF_B + (size_t)MTOK * DFF * 4;              // 100,663,296
static const size_t HIST_B  = WP_B + (size_t)1048576 * 4;                  // 104,857,600
static const size_t STATE_B = HIST_B + (size_t)36 * 4096 * 4;              // 105,447,424
static const size_t THR_B   = STATE_B + (size_t)36 * 32;                   // 105,448,576
static const size_t WS_NEED = THR_B + 18 * 8;

struct PState {
    double lo, hi;
    unsigned int rank;
    unsigned int pad;
    unsigned long long found;   // f64 bits of captured order statistic
};

// ---------------------------------------------------------------------------
// prune: |etched| chain.  f32 sin (matches numpy f32 sin of f32 product),
// then f64 for theta/cos/bloom/etched (numpy promotes via f64 linspace).
// ---------------------------------------------------------------------------
__device__ __forceinline__ double etched_abs(float wv, int i, double step, double invn)
{
    float b0 = sinf(wv * 3.14159274f);            // f32 pi, f32 product
    b0 = fminf(1.0f, fmaxf(-1.0f, b0));
    double theta = step * (double)i;              // linspace(0, s, s)[i] = i*s/(s-1)
    double c = cos(theta * invn + 2.0943951023931953);   // theta/s + 2*pi/3
    double bl = (double)b0;
    double bloom = bl + bl * c * 1.5;
    double e = cos(bloom * 9.869604401089358)     // pi^2
             + bloom * bloom * 0.003183098861837907;     // 0.01/pi
    return fabs(e);
}

// matrix table: m = 3*l + {0: in_proj(1536x512), 1: lin1(2048x512), 2: lin2(512x2048)}
__device__ __forceinline__ void prune_matrix(int m, const float* ipw, const float* w1,
                                             const float* w2, const float** w, int* n)
{
    int l = m / 3, j = m % 3;
    if (j == 0)      { *w = ipw + (size_t)l * 786432;  *n = 786432;  }
    else if (j == 1) { *w = w1  + (size_t)l * 1048576; *n = 1048576; }
    else             { *w = w2  + (size_t)l * 1048576; *n = 1048576; }
}

__global__ __launch_bounds__(256) void k_prune_init(unsigned int* hist, PState* st)
{
    int gid = blockIdx.x * 256 + threadIdx.x;
    for (int i = gid; i < 36 * 4096; i += gridDim.x * 256) hist[i] = 0u;
    if (gid < 36) {
        int m = gid >> 1;
        int n = (m % 3 == 0) ? 786432 : 1048576;
        st[gid].lo = 0.0;
        st[gid].hi = 1.03;                     // > max possible |etched| (~1.02)
        st[gid].rank = (unsigned)(n / 4 - 1 + (gid & 1));   // k0 and k0+1
        st[gid].found = 0x7FF0000000000000ULL; // +inf
    }
}

__global__ __launch_bounds__(256) void k_prune_hist(const float* ipw, const float* w1,
                                                    const float* w2, unsigned int* hist,
                                                    PState* st)
{
    int m = blockIdx.x >> 6;
    int chunk = blockIdx.x & 63;
    const float* w; int n;
    prune_matrix(m, ipw, w1, w2, &w, &n);
    __shared__ unsigned int h[2][4096];
    for (int i = threadIdx.x; i < 8192; i += 256) ((unsigned int*)h)[i] = 0u;
    __syncthreads();
    double lo0 = st[2*m].lo,   hi0 = st[2*m].hi;
    double lo1 = st[2*m+1].lo, hi1 = st[2*m+1].hi;
    double sc0 = 4096.0 / (hi0 - lo0);
    double sc1 = 4096.0 / (hi1 - lo1);
    double step = (double)n / (double)(n - 1);
    double invn = 1.0 / (double)n;
    int per = (n + 63) >> 6;
    int i0 = chunk * per;
    int i1 = min(n, i0 + per);
    for (int i = i0 + (int)threadIdx.x; i < i1; i += 256) {
        double a = etched_abs(w[i], i, step, invn);
        if (a >= lo0 && a < hi0) {
            int bin = (int)((a - lo0) * sc0); if (bin > 4095) bin = 4095;
            atomicAdd(&h[0][bin], 1u);
        }
        if (a >= lo1 && a < hi1) {
            int bin = (int)((a - lo1) * sc1); if (bin > 4095) bin = 4095;
            atomicAdd(&h[1][bin], 1u);
        }
    }
    __syncthreads();
    for (int i = threadIdx.x; i < 4096; i += 256) {
        if (h[0][i]) atomicAdd(&hist[(size_t)(2*m) * 4096 + i], h[0][i]);
        if (h[1][i]) atomicAdd(&hist[(size_t)(2*m+1) * 4096 + i], h[1][i]);
    }
}

__global__ __launch_bounds__(256) void k_prune_select(unsigned int* hist, PState* st)
{
    int s = blockIdx.x;
    __shared__ unsigned int h[4096];
    unsigned int* gh = hist + (size_t)s * 4096;
    for (int i = threadIdx.x; i < 4096; i += 256) { h[i] = gh[i]; gh[i] = 0u; }
    __syncthreads();
    if (threadIdx.x == 0) {
        PState ps = st[s];
        unsigned int r = ps.rank;
        unsigned int acc = 0;
        int bsel = -1; unsigned int newr = 0;
        for (int bi = 0; bi < 4096; ++bi) {
            unsigned int c = h[bi];
            if (bsel < 0 && r < acc + c) { bsel = bi; newr = r - acc; }
            acc += c;
        }
        if (bsel < 0) {   // fp-edge migration fallback
            for (int bi = 4095; bi >= 0; --bi)
                if (h[bi]) { bsel = bi; newr = h[bi] - 1; break; }
            if (bsel < 0) { bsel = 0; newr = 0; }
        }
        double width = (ps.hi - ps.lo) / 4096.0;
        st[s].lo = ps.lo + width * bsel;
        st[s].hi = ps.lo + width * (bsel + 1);
        st[s].rank = newr;
    }
}

__global__ __launch_bounds__(256) void k_prune_capture(const float* ipw, const float* w1,
                                                       const float* w2, PState* st)
{
    int m = blockIdx.x >> 6;
    int chunk = blockIdx.x & 63;
    const float* w; int n;
    prune_matrix(m, ipw, w1, w2, &w, &n);
    double lo0 = st[2*m].lo, lo1 = st[2*m+1].lo;
    double step = (double)n / (double)(n - 1);
    double invn = 1.0 / (double)n;
    unsigned long long mn0 = 0x7FF0000000000000ULL, mn1 = 0x7FF0000000000000ULL;
    int per = (n + 63) >> 6;
    int i0 = chunk * per;
    int i1 = min(n, i0 + per);
    for (int i = i0 + (int)threadIdx.x; i < i1; i += 256) {
        double a = etched_abs(w[i], i, step, invn);
        unsigned long long bits = (unsigned long long)__double_as_longlong(a);
        if (a >= lo0 && bits < mn0) mn0 = bits;
        if (a >= lo1 && bits < mn1) mn1 = bits;
    }
    __shared__ unsigned long long sm[2];
    if (threadIdx.x == 0) { sm[0] = 0x7FF0000000000000ULL; sm[1] = 0x7FF0000000000000ULL; }
    __syncthreads();
    atomicMin(&sm[0], mn0);
    atomicMin(&sm[1], mn1);
    __syncthreads();
    if (threadIdx.x == 0) {
        atomicMin(&st[2*m].found, sm[0]);
        atomicMin(&st[2*m+1].found, sm[1]);
    }
}

__global__ void k_prune_thr(PState* st, double* thr)
{
    int m = threadIdx.x;
    if (m < 18) {
        double v0 = __longlong_as_double((long long)st[2*m].found);
        double v1 = __longlong_as_double((long long)st[2*m+1].found);
        thr[m] = v0 + 0.75 * (v1 - v0);    // np.quantile linear interp, frac=0.75
    }
}

__global__ __launch_bounds__(256) void k_apply_mask(const float* __restrict__ w,
                                                    float* __restrict__ out,
                                                    const double* __restrict__ thr,
                                                    int m, int n)
{
    double T = thr[m];
    double step = (double)n / (double)(n - 1);
    double invn = 1.0 / (double)n;
    for (int i = blockIdx.x * 256 + threadIdx.x; i < n; i += gridDim.x * 256) {
        double a = etched_abs(w[i], i, step, invn);
        out[i] = (a > T) ? w[i] : 0.0f;
    }
}

// ---------------------------------------------------------------------------
// embedding
// ---------------------------------------------------------------------------
__global__ __launch_bounds__(256) void k_embed(const int* __restrict__ src,
                                               const float* __restrict__ emb,
                                               const float* __restrict__ pos,
                                               float* __restrict__ x)
{
    int t = blockIdx.x;
    int tid = threadIdx.x;
    int v = src[t];
    int s = t & 511;
    const float* e = emb + (size_t)v * DMODEL;
    const float* p = pos + (size_t)s * DMODEL;
    float* xo = x + (size_t)t * DMODEL;
    xo[tid]       = e[tid]       * 22.627416997969522f + p[tid];
    xo[tid + 256] = e[tid + 256] * 22.627416997969522f + p[tid + 256];
}

// ---------------------------------------------------------------------------
// GEMM: C[M,N] = A[M,K] @ B[N,K]^T + bias[N]  (optional relu)
// ---------------------------------------------------------------------------
__global__ __launch_bounds__(256) void k_gemm(const float* __restrict__ A,
                                              const float* __restrict__ B,
                                              const float* __restrict__ bias,
                                              float* __restrict__ C,
                                              int M, int N, int K, int relu)
{
    __shared__ float As[16][132];
    __shared__ float Bs[16][132];
    int colBase = blockIdx.x * 128;
    int rowBase = blockIdx.y * 128;
    int t = threadIdx.x;
    int tr = (t >> 4) << 2;   // 0..60
    int tc = (t & 15) << 2;   // 0..60
    float acc[8][8];
#pragma unroll
    for (int r = 0; r < 8; ++r)
#pragma unroll
        for (int c = 0; c < 8; ++c) acc[r][c] = 0.0f;

    for (int k0 = 0; k0 < K; k0 += 16) {
        __syncthreads();
#pragma unroll
        for (int u = 0; u < 2; ++u) {
            int f = t + u * 256;          // 0..511 float4 slots (128 rows x 4)
            int row = f >> 2;
            int c4 = (f & 3) << 2;
            float4 av = *(const float4*)(A + (size_t)(rowBase + row) * K + (k0 + c4));
            As[c4 + 0][row] = av.x; As[c4 + 1][row] = av.y;
            As[c4 + 2][row] = av.z; As[c4 + 3][row] = av.w;
            int nrow = colBase + row;
            float4 bv = make_float4(0.f, 0.f, 0.f, 0.f);
            if (nrow < N) bv = *(const float4*)(B + (size_t)nrow * K + (k0 + c4));
            Bs[c4 + 0][row] = bv.x; Bs[c4 + 1][row] = bv.y;
            Bs[c4 + 2][row] = bv.z; Bs[c4 + 3][row] = bv.w;
        }
        __syncthreads();
#pragma unroll
        for (int kk = 0; kk < 16; ++kk) {
            float4 a0 = *(const float4*)&As[kk][tr];
            float4 a1 = *(const float4*)&As[kk][tr + 64];
            float4 b0 = *(const float4*)&Bs[kk][tc];
            float4 b1 = *(const float4*)&Bs[kk][tc + 64];
            float ar[8] = {a0.x, a0.y, a0.z, a0.w, a1.x, a1.y, a1.z, a1.w};
            float br[8] = {b0.x, b0.y, b0.z, b0.w, b1.x, b1.y, b1.z, b1.w};
#pragma unroll
            for (int r = 0; r < 8; ++r)
#pragma unroll
                for (int c = 0; c < 8; ++c)
                    acc[r][c] = fmaf(ar[r], br[c], acc[r][c]);
        }
    }
#pragma unroll
    for (int r = 0; r < 8; ++r) {
        int row = rowBase + ((r >> 2) << 6) + tr + (r & 3);
#pragma unroll
        for (int c = 0; c < 8; ++c) {
            int col = colBase + ((c >> 2) << 6) + tc + (c & 3);
            if (col < N) {
                float v = acc[r][c] + bias[col];
                if (relu) v = fmaxf(v, 0.0f);
                C[(size_t)row * N + col] = v;
            }
        }
    }
}

// ---------------------------------------------------------------------------
// flash attention v2: GEMM-style register tiling, no cross-lane shuffles.
// block = 256 threads, 64 q-rows per block; K/V in 64-row LDS tiles.
// thread (tx,ty): tx=t&15, ty=t>>4. Score tile: rows ty*4.., cols tx*4...
// O tile: rows ty*4.., d-cols tx*4... Row stats via LDS reduction.
// qkv layout: [8192][1536] (q|k|v each 512, head h at h*64).
// ---------------------------------------------------------------------------
__global__ __launch_bounds__(256) void k_attn(const float* __restrict__ qkv,
                                              float* __restrict__ out)
{
    __shared__ float Qs[64][68];   // [d][r]  (transposed)
    __shared__ float KP[64][68];   // K: [d][c] transposed; reused as P: [r][c]
    __shared__ float Vs[64][64];   // [c][d]
    __shared__ float red[64][17];  // row-reduction scratch
    __shared__ float mS[64], lS[64], aS[64];

    int bh = blockIdx.x;           // 0..127
    int b = bh >> 3, h = bh & 7;
    int qt = blockIdx.y;           // 0..7 (64-row q tiles)
    int t = threadIdx.x;
    int tx = t & 15, ty = t >> 4;
    int r0 = ty * 4, c0 = tx * 4;  // c0 doubles as d0 in PV/epilogue
    int rowq = b * 512 + qt * 64;

    size_t baseq = (size_t)rowq * 1536 + h * 64;
    // load Q transposed: 4096 floats, 4 float4 per thread, coalesced
#pragma unroll
    for (int u = 0; u < 4; ++u) {
        int f = t + u * 256;             // float4 slot 0..1023
        int r = f >> 4;                  // 0..63
        int d4 = (f & 15) << 2;
        float4 q4 = *(const float4*)(qkv + baseq + (size_t)r * 1536 + d4);
        Qs[d4 + 0][r] = q4.x; Qs[d4 + 1][r] = q4.y;
        Qs[d4 + 2][r] = q4.z; Qs[d4 + 3][r] = q4.w;
    }
    float O[4][4];
#pragma unroll
    for (int i = 0; i < 4; ++i)
#pragma unroll
        for (int j = 0; j < 4; ++j) O[i][j] = 0.0f;
    if (t < 64) { mS[t] = -INFINITY; lS[t] = 0.0f; }

    size_t basek = (size_t)(b * 512) * 1536 + h * 64;
    for (int kt = 0; kt < 8; ++kt) {
        __syncthreads();   // KP/Vs from prev iter fully consumed; mS init visible
        // stage K (transposed) and V
#pragma unroll
        for (int u = 0; u < 4; ++u) {
            int f = t + u * 256;
            int r = f >> 4;
            int d4 = (f & 15) << 2;
            size_t g = basek + (size_t)(kt * 64 + r) * 1536 + d4;
            float4 k4 = *(const float4*)(qkv + g + 512);
            KP[d4 + 0][r] = k4.x; KP[d4 + 1][r] = k4.y;
            KP[d4 + 2][r] = k4.z; KP[d4 + 3][r] = k4.w;
            float4 v4 = *(const float4*)(qkv + g + 1024);
            *(float4*)&Vs[r][d4] = v4;
        }
        __syncthreads();
        // S = (Q K^T) * scale — per-thread 4x4 outer-product accumulation
        float S[4][4];
#pragma unroll
        for (int i = 0; i < 4; ++i)
#pragma unroll
            for (int j = 0; j < 4; ++j) S[i][j] = 0.0f;
#pragma unroll 16
        for (int d = 0; d < 64; ++d) {
            float4 qa = *(const float4*)&Qs[d][r0];
            float4 kb = *(const float4*)&KP[d][c0];
            const float* qa_ = &qa.x;
            const float* kb_ = &kb.x;
#pragma unroll
            for (int i = 0; i < 4; ++i)
#pragma unroll
                for (int j = 0; j < 4; ++j)
                    S[i][j] = fmaf(qa_[i], kb_[j], S[i][j]);
        }
        // per-thread row max over 4 cols
#pragma unroll
        for (int i = 0; i < 4; ++i) {
            float mx = fmaxf(fmaxf(S[i][0], S[i][1]), fmaxf(S[i][2], S[i][3]));
            red[r0 + i][tx] = mx * 0.125f;
        }
        __syncthreads();   // also: everyone done reading KP (K dead)
        if (t < 64) {
            float m = red[t][0];
#pragma unroll
            for (int k = 1; k < 16; ++k) m = fmaxf(m, red[t][k]);
            float mo = mS[t];
            float mn = fmaxf(mo, m);
            aS[t] = __expf(mo - mn);
            mS[t] = mn;
        }
        __syncthreads();
        // p = exp(s*scale - m); write P into KP[r][c]; partial row sums
#pragma unroll
        for (int i = 0; i < 4; ++i) {
            float mn = mS[r0 + i];
            float rs = 0.0f;
#pragma unroll
            for (int j = 0; j < 4; ++j) {
                float p = __expf(fmaf(S[i][j], 0.125f, -mn));
                S[i][j] = p;
                rs += p;
            }
            red[r0 + i][tx] = rs;
            *(float4*)&KP[r0 + i][c0] = *(float4*)S[i];
        }
        __syncthreads();
        if (t < 64) {
            float s = red[t][0];
#pragma unroll
            for (int k = 1; k < 16; ++k) s += red[t][k];
            lS[t] = lS[t] * aS[t] + s;
        }
        // PV: O[r][d] = O*alpha + sum_c P[r][c] * V[c][d]
        float pv[4][4];
#pragma unroll
        for (int i = 0; i < 4; ++i)
#pragma unroll
            for (int j = 0; j < 4; ++j) pv[i][j] = 0.0f;
#pragma unroll 4
        for (int c4 = 0; c4 < 64; c4 += 4) {
            float pr[4][4];
#pragma unroll
            for (int i = 0; i < 4; ++i)
                *(float4*)pr[i] = *(const float4*)&KP[r0 + i][c4];
#pragma unroll
            for (int cc = 0; cc < 4; ++cc) {
                float4 v = *(const float4*)&Vs[c4 + cc][c0];
                const float* v_ = &v.x;
#pragma unroll
                for (int i = 0; i < 4; ++i)
#pragma unroll
                    for (int j = 0; j < 4; ++j)
                        pv[i][j] = fmaf(pr[i][cc], v_[j], pv[i][j]);
            }
        }
#pragma unroll
        for (int i = 0; i < 4; ++i) {
            float a = aS[r0 + i];
#pragma unroll
            for (int j = 0; j < 4; ++j) O[i][j] = O[i][j] * a + pv[i][j];
        }
    }
    __syncthreads();   // final lS update visible
#pragma unroll
    for (int i = 0; i < 4; ++i) {
        float inv = 1.0f / lS[r0 + i];
        float4 o;
        o.x = O[i][0] * inv; o.y = O[i][1] * inv;
        o.z = O[i][2] * inv; o.w = O[i][3] * inv;
        *(float4*)(out + (size_t)(rowq + r0 + i) * 512 + h * 64 + c0) = o;
    }
}

// ---------------------------------------------------------------------------
// residual + layernorm
// ---------------------------------------------------------------------------
__global__ __launch_bounds__(256) void k_ln(const float* x, const float* r,
                                            const float* __restrict__ g,
                                            const float* __restrict__ b,
                                            float* out)
{
    int t = blockIdx.x, tid = threadIdx.x;
    size_t base = (size_t)t * DMODEL;
    float a0 = x[base + tid]       + r[base + tid];
    float a1 = x[base + tid + 256] + r[base + tid + 256];
    float s = a0 + a1;
    float q = fmaf(a0, a0, a1 * a1);
#pragma unroll
    for (int off = 32; off; off >>= 1) {
        s += __shfl_xor(s, off, 64);
        q += __shfl_xor(q, off, 64);
    }
    __shared__ float sw[8];
    int w = tid >> 6, lane = tid & 63;
    if (lane == 0) { sw[w] = s; sw[4 + w] = q; }
    __syncthreads();
    s = sw[0] + sw[1] + sw[2] + sw[3];
    q = sw[4] + sw[5] + sw[6] + sw[7];
    float mean = s * (1.0f / 512.0f);
    float var = q * (1.0f / 512.0f) - mean * mean;
    float inv = 1.0f / sqrtf(var + 1e-5f);
    out[base + tid]       = (a0 - mean) * inv * g[tid]       + b[tid];
    out[base + tid + 256] = (a1 - mean) * inv * g[tid + 256] + b[tid + 256];
}

// ---------------------------------------------------------------------------
// host side
// ---------------------------------------------------------------------------
static inline void launch_gemm(const float* A, const float* B, const float* bias,
                               float* C, int M, int N, int K, int relu,
                               hipStream_t stream)
{
    dim3 grid((N + 127) / 128, M / 128);
    k_gemm<<<grid, 256, 0, stream>>>(A, B, bias, C, M, N, K, relu);
}

extern "C" void kernel_launch(void* const* d_in, const int* in_sizes, int n_in,
                              void* d_out, int out_size, void* d_ws, size_t ws_size,
                              hipStream_t stream)
{
    (void)in_sizes; (void)n_in; (void)out_size;
    if (ws_size < WS_NEED) return;   // need ~106 MB of workspace

    const int*   src = (const int*)  d_in[0];
    const float* emb = (const float*)d_in[1];
    const float* pos = (const float*)d_in[2];
    const float* ipw = (const float*)d_in[3];
    const float* ipb = (const float*)d_in[4];
    const float* opw = (const float*)d_in[5];
    const float* opb = (const float*)d_in[6];
    const float* g1  = (const float*)d_in[7];
    const float* b1  = (const float*)d_in[8];
    const float* g2  = (const float*)d_in[9];
    const float* b2  = (const float*)d_in[10];
    const float* w1  = (const float*)d_in[11];
    const float* bb1 = (const float*)d_in[12];
    const float* w2  = (const float*)d_in[13];
    const float* bb2 = (const float*)d_in[14];
    const float* ow  = (const float*)d_in[15];
    const float* ob  = (const float*)d_in[16];

    char* ws = (char*)d_ws;
    float* X   = (float*)(ws + X_B);
    float* Y   = (float*)(ws + Y_B);
    float* BUF = (float*)(ws + BUF_B);
    float* WP  = (float*)(ws + WP_B);
    unsigned int* HIST = (unsigned int*)(ws + HIST_B);
    PState* ST = (PState*)(ws + STATE_B);
    double* THR = (double*)(ws + THR_B);
    float* OUT = (float*)d_out;

    // embedding
    k_embed<<<MTOK, 256, 0, stream>>>(src, emb, pos, X);

    // prune thresholds for all 18 matrices (batched 3-level histogram select)
    k_prune_init<<<64, 256, 0, stream>>>(HIST, ST);
    for (int lev = 0; lev < 3; ++lev) {
        k_prune_hist<<<18 * 64, 256, 0, stream>>>(ipw, w1, w2, HIST, ST);
        k_prune_select<<<36, 256, 0, stream>>>(HIST, ST);
    }
    k_prune_capture<<<18 * 64, 256, 0, stream>>>(ipw, w1, w2, ST);
    k_prune_thr<<<1, 32, 0, stream>>>(ST, THR);

    for (int l = 0; l < NLAYER; ++l) {
        // qkv = x @ prune(in_proj_w)^T + b
        k_apply_mask<<<1024, 256, 0, stream>>>(ipw + (size_t)l * 786432, WP, THR,
                                               3 * l + 0, 786432);
        launch_gemm(X, WP, ipb + (size_t)l * 1536, BUF, MTOK, 1536, DMODEL, 0, stream);
        // attention
        k_attn<<<dim3(128, 8), 256, 0, stream>>>(BUF, Y);
        // out projection (raw weights) -> BUF (z)
        launch_gemm(Y, opw + (size_t)l * 262144, opb + (size_t)l * 512, BUF,
                    MTOK, DMODEL, DMODEL, 0, stream);
        // x = LN(x + z)
        k_ln<<<MTOK, 256, 0, stream>>>(X, BUF, g1 + (size_t)l * 512,
                                       b1 + (size_t)l * 512, X);
        // ff1 = relu(x @ prune(lin1_w)^T + b)
        k_apply_mask<<<1024, 256, 0, stream>>>(w1 + (size_t)l * 1048576, WP, THR,
                                               3 * l + 1, 1048576);
        launch_gemm(X, WP, bb1 + (size_t)l * 2048, BUF, MTOK, DFF, DMODEL, 1, stream);
        // ff2 = ff1 @ prune(lin2_w)^T + b -> Y
        k_apply_mask<<<1024, 256, 0, stream>>>(w2 + (size_t)l * 1048576, WP, THR,
                                               3 * l + 2, 1048576);
        launch_gemm(BUF, WP, bb2 + (size_t)l * 512, Y, MTOK, DMODEL, DFF, 0, stream);
        // x = LN(x + ff)
        k_ln<<<MTOK, 256, 0, stream>>>(X, Y, g2 + (size_t)l * 512,
                                       b2 + (size_t)l * 512, X);
    }

    // logits = x @ out_w^T + out_b
    launch_gemm(X, ow, ob, OUT, MTOK, VOCAB, DMODEL, 0, stream);
}